// Round 15
// baseline (494.914 us; speedup 1.0000x reference)
//
#include <hip/hip_runtime.h>
#include <hip/hip_bf16.h>

typedef __attribute__((ext_vector_type(8))) short short8_t;
typedef __attribute__((ext_vector_type(4))) float f32x4;

#define DEV __device__ __forceinline__

constexpr int BB = 8;           // batch
constexpr int NV = 10242;       // vertices
constexpr int NE = 61440;       // edges
constexpr int NET = NE + NV;    // total CSR edges (with self-loops)
constexpr int MROWS = BB * NV;  // 81936
constexpr int KD = 512;         // K for 512-wide GEMMs

DEV float bf2f(ushort u) { union { unsigned i; float f; } v; v.i = ((unsigned)u) << 16; return v.f; }
DEV ushort f2bf(float f) {
    union { unsigned i; float f; } v; v.f = f;
    unsigned b = v.i;
    b += 0x7fffu + ((b >> 16) & 1u);   // RNE
    return (ushort)(b >> 16);
}

// ---------------- CSR build ----------------
__global__ void k_init(int* deg, int* fill) {
    int i = blockIdx.x * 256 + threadIdx.x;
    if (i < NV) { deg[i] = 1; fill[i] = 0; }   // self-loop counts as 1
}

__global__ void k_count(const int* __restrict__ ei, int* __restrict__ deg) {
    int e = blockIdx.x * 256 + threadIdx.x;
    if (e < NE) atomicAdd(&deg[ei[NE + e]], 1);   // dst row
}

__global__ __launch_bounds__(1024) void k_scan(const int* __restrict__ cnt, int* __restrict__ rp) {
    __shared__ int part[1024];
    const int t = threadIdx.x;
    const int chunk = (NV + 1023) / 1024;   // 11
    int b0 = t * chunk, b1 = min(b0 + chunk, NV);
    int s = 0;
    for (int i = b0; i < b1; ++i) s += cnt[i];
    part[t] = s;
    __syncthreads();
    for (int off = 1; off < 1024; off <<= 1) {
        int v = (t >= off) ? part[t - off] : 0;
        __syncthreads();
        part[t] += v;
        __syncthreads();
    }
    int run = (t == 0) ? 0 : part[t - 1];
    for (int i = b0; i < b1; ++i) { rp[i] = run; run += cnt[i]; }
    if (t == 1023) rp[NV] = part[1023];
}

__global__ void k_fill(const int* __restrict__ ei, const int* __restrict__ rp,
                       int* __restrict__ fill, const int* __restrict__ deg,
                       int* __restrict__ ci, float* __restrict__ val) {
    int e = blockIdx.x * 256 + threadIdx.x;
    if (e >= NET) return;
    int s, d;
    if (e < NE) { s = ei[e]; d = ei[NE + e]; }
    else        { s = d = e - NE; }           // self-loops
    int p = atomicAdd(&fill[d], 1);
    int pos = rp[d] + p;
    ci[pos] = s;
    val[pos] = rsqrtf((float)deg[s]) * rsqrtf((float)deg[d]);
}

// ---------------- merged 3-wide agg + scalar chain ----------------
__global__ __launch_bounds__(256) void k_aggsc(const float* __restrict__ src, float* __restrict__ dst,
                                               const int* __restrict__ rp, const int* __restrict__ ci,
                                               const float* __restrict__ val,
                                               const float* __restrict__ sin, float* __restrict__ sout,
                                               int gMR_) {
    const int bid = blockIdx.x;
    if (bid < gMR_) {
        int idx = bid * 256 + threadIdx.x;
        if (idx >= MROWS) return;
        int b = idx / NV, i = idx - b * NV;
        float a0 = 0.f, a1 = 0.f, a2 = 0.f;
        const float* sb = src + (size_t)b * NV * 3;
        for (int e = rp[i]; e < rp[i + 1]; ++e) {
            int j = ci[e];
            float wv = val[e];
            a0 = fmaf(wv, sb[j * 3 + 0], a0);
            a1 = fmaf(wv, sb[j * 3 + 1], a1);
            a2 = fmaf(wv, sb[j * 3 + 2], a2);
        }
        float* o = dst + ((size_t)b * NV + i) * 3;
        o[0] = a0; o[1] = a1; o[2] = a2;
    } else {
        int i = (bid - gMR_) * 256 + threadIdx.x;
        if (i >= NV) return;
        float a = 0.f;
        if (sin) { for (int e = rp[i]; e < rp[i + 1]; ++e) a = fmaf(val[e], sin[ci[e]], a); }
        else     { for (int e = rp[i]; e < rp[i + 1]; ++e) a += val[e]; }
        sout[i] = a;
    }
}

// ---------------- merged prep: weight convert + small matvecs + l1base ----------------
__global__ __launch_bounds__(256) void k_prep(const float* __restrict__ W4, const float* __restrict__ W3,
                                              const float* __restrict__ W5, const float* __restrict__ W1,
                                              const float* __restrict__ b1, const float* __restrict__ b3,
                                              const float* __restrict__ W2, const float* __restrict__ img,
                                              ushort* __restrict__ Wt4, ushort* __restrict__ W3c,
                                              ushort* __restrict__ Wt5, float* __restrict__ CW12,
                                              float* __restrict__ b1w2, float* __restrict__ b3w4,
                                              float* __restrict__ basev) {
    constexpr int WB = (2 * 512 * 512 + 64 * 512) / 256;   // 2176
    const int bid = blockIdx.x;
    const int t = threadIdx.x;
    if (bid < WB) {
        int idx = bid * 256 + t;
        if (idx < 512 * 512) {
            int n = idx >> 9, k = idx & 511;
            Wt4[idx] = f2bf(W4[k * 512 + n]);
        } else if (idx < 2 * 512 * 512) {
            int j = idx - 512 * 512;
            W3c[j] = f2bf(W3[j]);
        } else {
            int j = idx - 2 * 512 * 512;
            int n = j >> 9, k = j & 511;
            Wt5[j] = f2bf(W5[k * 64 + n]);
        }
    } else if (bid < WB + 10) {
        int r = bid - WB;
        int y = r >> 1;
        int c = (r & 1) * 256 + t;
        const float* Mrow = (y < 3) ? (W1 + y * 512) : (y == 3 ? b1 : b3);
        const float* W = (y < 4) ? W2 : W4;
        float a = 0.f;
        for (int k = 0; k < 512; ++k) a = fmaf(Mrow[k], W[(size_t)k * 512 + c], a);
        float* o = (y < 3) ? (CW12 + y * 512) : (y == 3 ? b1w2 : b3w4);
        o[c] = a;
    } else {
        int r = bid - (WB + 10);
        int b = r >> 1;
        int c = (r & 1) * 256 + t;
        float s = 0.f;
        for (int k = 0; k < 512; ++k) s = fmaf(img[b * 512 + k], W1[(size_t)(3 + k) * 512 + c], s);
        basev[b * 512 + c] = s;
    }
}

// bw2[r][c] = sum_k basev[r][k]*W2[k][c]
__global__ __launch_bounds__(128) void k_matvecs(const float* __restrict__ M, const float* __restrict__ W,
                                                 float* __restrict__ out) {
    int c = blockIdx.x * 128 + threadIdx.x;
    int r = blockIdx.y;
    float a = 0.f;
    for (int k = 0; k < 512; ++k) a = fmaf(M[r * 512 + k], W[(size_t)k * 512 + c], a);
    out[r * 512 + c] = a;
}

// ---------------- x2 reconstruction (layers 1-2 collapsed), R = relu(x2) -> bf16 ----------------
__global__ __launch_bounds__(256) void k_x2(const float* __restrict__ aggV2, const float* __restrict__ s,
                                            const float* __restrict__ s2, const float* __restrict__ CW12,
                                            const float* __restrict__ bw2, const float* __restrict__ b1w2,
                                            const float* __restrict__ b2, ushort* __restrict__ r2) {
    const int t = threadIdx.x;
    int row = blockIdx.x * 2 + (t >> 7);
    if (row >= MROWS) return;
    int i = row >> 3, b = row & 7;
    const float* av = aggV2 + ((size_t)b * NV + i) * 3;
    float a0 = av[0], a1 = av[1], a2 = av[2];
    float si = s[i], s2i = s2[i];
    int c = (t & 127) * 4;
    float4 w0 = *(const float4*)&CW12[c];
    float4 w1 = *(const float4*)&CW12[512 + c];
    float4 w2 = *(const float4*)&CW12[1024 + c];
    float4 bw = *(const float4*)&bw2[b * 512 + c];
    float4 bv = *(const float4*)&b1w2[c];
    float4 b2v = *(const float4*)&b2[c];
    float o0 = a0 * w0.x + a1 * w1.x + a2 * w2.x + s2i * bw.x + si * bv.x + b2v.x;
    float o1 = a0 * w0.y + a1 * w1.y + a2 * w2.y + s2i * bw.y + si * bv.y + b2v.y;
    float o2 = a0 * w0.z + a1 * w1.z + a2 * w2.z + s2i * bw.z + si * bv.z + b2v.z;
    float o3 = a0 * w0.w + a1 * w1.w + a2 * w2.w + s2i * bw.w + si * bv.w + b2v.w;
    ushort4 o;
    o.x = f2bf(fmaxf(o0, 0.f));
    o.y = f2bf(fmaxf(o1, 0.f));
    o.z = f2bf(fmaxf(o2, 0.f));
    o.w = f2bf(fmaxf(o3, 0.f));
    *(ushort4*)&r2[(size_t)row * 512 + c] = o;
}

#define WAITVM(n) do { \
    asm volatile("s_waitcnt vmcnt(" #n ")" ::: "memory"); \
    __builtin_amdgcn_sched_barrier(0); \
    __builtin_amdgcn_s_barrier(); \
    __builtin_amdgcn_sched_barrier(0); \
} while (0)

// ---------------- GEMM: C[M,Nc] = A[M,512] @ Bt[Nc,512]^T ----------------
// BM=256 x BN=128 tile, 4 waves, wave tile 64x128 (acc[4][8]): 12 ds_reads per
// 32 MFMA (2.67 MFMA/read vs 2.0 at 128x128) -- R14 profile showed the GEMM is
// LDS-read-bound (MfmaUtil 20%, ~96KB LDS reads per K-step vs ~230cy MFMA).
// XOR-swizzled LDS, swapped-MFMA C^T frags, ushort4 stores, T4 counted-vmcnt
// 3-buffer pipeline (6 loads/thread/stage -> vmcnt(6)).
template <int EPI>
__global__ __launch_bounds__(256) void k_gemm(const ushort* __restrict__ A, const ushort* __restrict__ Bt,
                                              ushort* __restrict__ C, int Mr, int Nc,
                                              const float* __restrict__ sv, const float* __restrict__ eb1,
                                              const float* __restrict__ eb2) {
    const int ncb = (Nc + 127) >> 7;
    const int nrc = (Mr + 255) >> 8;
    const int cpx = (nrc + 7) >> 3;
    const int bid = blockIdx.x;
    const int xcd = bid & 7;
    const int k = bid >> 3;
    const int rc = xcd * cpx + k / ncb;
    const int cb = k % ncb;
    if (rc >= nrc) return;

    __shared__ __align__(16) ushort lA[3][8192];   // [256 rows][32k] swizzled
    __shared__ __align__(16) ushort lB[3][4096];   // [128 rows][32k] swizzled
    const int t = threadIdx.x;
    const int lane = t & 63, w = t >> 6;
    const int r0 = rc * 256, c0 = cb * 128;

    const ushort* gA[4]; int loffA[4];
    #pragma unroll
    for (int p = 0; p < 4; ++p) {
        int idx = p * 256 + t;
        int row = idx >> 2, slot = idx & 3;
        int srcslot = slot ^ ((row >> 1) & 3);
        int ar = min(r0 + row, Mr - 1);
        gA[p] = A + (size_t)ar * KD + srcslot * 8;
        loffA[p] = idx * 8;
    }
    const ushort* gB[2]; int loffB[2];
    #pragma unroll
    for (int p = 0; p < 2; ++p) {
        int idx = p * 256 + t;
        int row = idx >> 2, slot = idx & 3;
        int srcslot = slot ^ ((row >> 1) & 3);
        int bc = min(c0 + row, Nc - 1);
        gB[p] = Bt + (size_t)bc * KD + srcslot * 8;
        loffB[p] = idx * 8;
    }

    auto stage = [&](int buf, int kt) {
        int ko = kt * 32;
        #pragma unroll
        for (int p = 0; p < 4; ++p)
            __builtin_amdgcn_global_load_lds(
                (const __attribute__((address_space(1))) void*)(gA[p] + ko),
                (__attribute__((address_space(3))) void*)(&lA[buf][loffA[p]]), 16, 0, 0);
        #pragma unroll
        for (int p = 0; p < 2; ++p)
            __builtin_amdgcn_global_load_lds(
                (const __attribute__((address_space(1))) void*)(gB[p] + ko),
                (__attribute__((address_space(3))) void*)(&lB[buf][loffB[p]]), 16, 0, 0);
    };

    f32x4 acc[4][8] = {};
    const int rloc = lane & 15;
    const int kb = lane >> 4;
    const int kbs = (kb ^ ((rloc >> 1) & 3)) * 8;

    auto compute = [&](int buf) {
        short8_t bfr[8];
        #pragma unroll
        for (int n = 0; n < 8; ++n)
            bfr[n] = *(const short8_t*)&lB[buf][(n * 16 + rloc) * 32 + kbs];
        #pragma unroll
        for (int m = 0; m < 4; ++m) {
            const short8_t af = *(const short8_t*)&lA[buf][(w * 64 + m * 16 + rloc) * 32 + kbs];
            #pragma unroll
            for (int n = 0; n < 8; ++n)   // swapped operands -> C^T fragment
                acc[m][n] = __builtin_amdgcn_mfma_f32_16x16x32_bf16(bfr[n], af, acc[m][n], 0, 0, 0);
        }
    };

    stage(0, 0);
    stage(1, 1);
    WAITVM(6);
    int cur = 0;
    for (int kt = 0; kt < 14; ++kt) {
        int sb = cur + 2; if (sb > 2) sb -= 3;
        stage(sb, kt + 2);
        compute(cur);
        WAITVM(6);
        cur = (cur == 2) ? 0 : cur + 1;
    }
    compute(cur);
    WAITVM(0);
    cur = (cur == 2) ? 0 : cur + 1;
    compute(cur);

    #pragma unroll
    for (int m = 0; m < 4; ++m) {
        const int gr = r0 + w * 64 + m * 16 + rloc;
        if (gr >= Mr) continue;
        #pragma unroll
        for (int n = 0; n < 8; ++n) {
            const int qc = c0 + n * 16;
            if (qc >= Nc) continue;
            const int gc = qc + kb * 4;
            float v0 = acc[m][n][0], v1 = acc[m][n][1], v2 = acc[m][n][2], v3 = acc[m][n][3];
            if (EPI == 1) {
                const float s = sv[gr >> 3];
                const float4 e1 = *(const float4*)&eb1[gc];
                const float4 e2 = *(const float4*)&eb2[gc];
                v0 = fmaxf(v0 + s * e1.x + e2.x, 0.f);
                v1 = fmaxf(v1 + s * e1.y + e2.y, 0.f);
                v2 = fmaxf(v2 + s * e1.z + e2.z, 0.f);
                v3 = fmaxf(v3 + s * e1.w + e2.w, 0.f);
            }
            ushort4 o;
            o.x = f2bf(v0); o.y = f2bf(v1); o.z = f2bf(v2); o.w = f2bf(v3);
            *(ushort4*)&C[(size_t)gr * Nc + gc] = o;
        }
    }
}

// ---------------- specialized GEMM for Nc=64 (unchanged, proven) ----------------
__global__ __launch_bounds__(256) void k_gemm64(const ushort* __restrict__ A, const ushort* __restrict__ Bt,
                                                ushort* __restrict__ C) {
    const int rc = blockIdx.x;
    const int r0 = rc * 256;
    __shared__ __align__(16) ushort lA[2][8192];
    __shared__ __align__(16) ushort lB[2][2048];
    const int t = threadIdx.x;
    const int lane = t & 63, w = t >> 6;

    const ushort* gA[4]; int loffA[4];
    #pragma unroll
    for (int p = 0; p < 4; ++p) {
        int idx = p * 256 + t;
        int row = idx >> 2, slot = idx & 3;
        int srcslot = slot ^ ((row >> 1) & 3);
        int ar = min(r0 + row, MROWS - 1);
        gA[p] = A + (size_t)ar * KD + srcslot * 8;
        loffA[p] = idx * 8;
    }
    const int brow = t >> 2, bslot = (t & 3) ^ ((brow >> 1) & 3);
    const ushort* gB = Bt + (size_t)brow * KD + bslot * 8;
    const int loffB = t * 8;

    auto stage = [&](int buf, int kt) {
        int ko = kt * 32;
        #pragma unroll
        for (int p = 0; p < 4; ++p)
            __builtin_amdgcn_global_load_lds(
                (const __attribute__((address_space(1))) void*)(gA[p] + ko),
                (__attribute__((address_space(3))) void*)(&lA[buf][loffA[p]]), 16, 0, 0);
        __builtin_amdgcn_global_load_lds(
            (const __attribute__((address_space(1))) void*)(gB + ko),
            (__attribute__((address_space(3))) void*)(&lB[buf][loffB]), 16, 0, 0);
    };

    f32x4 acc[4][4] = {};
    stage(0, 0);
    __syncthreads();
    int cur = 0;
    const int rloc = lane & 15;
    const int kb = lane >> 4;
    const int kbs = (kb ^ ((rloc >> 1) & 3)) * 8;
    for (int kt = 0; kt < 16; ++kt) {
        if (kt < 15) stage(cur ^ 1, kt + 1);
        short8_t af[4], bfr[4];
        #pragma unroll
        for (int m = 0; m < 4; ++m) {
            af[m]  = *(const short8_t*)&lA[cur][(w * 64 + m * 16 + rloc) * 32 + kbs];
            bfr[m] = *(const short8_t*)&lB[cur][(m * 16 + rloc) * 32 + kbs];
        }
        #pragma unroll
        for (int m = 0; m < 4; ++m)
            #pragma unroll
            for (int n = 0; n < 4; ++n)
                acc[m][n] = __builtin_amdgcn_mfma_f32_16x16x32_bf16(bfr[n], af[m], acc[m][n], 0, 0, 0);
        __syncthreads();
        cur ^= 1;
    }

    #pragma unroll
    for (int m = 0; m < 4; ++m) {
        const int gr = r0 + w * 64 + m * 16 + rloc;
        if (gr >= MROWS) continue;
        #pragma unroll
        for (int n = 0; n < 4; ++n) {
            const int gc = n * 16 + kb * 4;
            ushort4 o;
            o.x = f2bf(acc[m][n][0]); o.y = f2bf(acc[m][n][1]);
            o.z = f2bf(acc[m][n][2]); o.w = f2bf(acc[m][n][3]);
            *(ushort4*)&C[(size_t)gr * 64 + gc] = o;
        }
    }
}

// ---------------- PANEL-partitioned 512-wide aggregation (XCD-L2-resident gathers) ----------------
constexpr int NVG16 = (NV + 15) / 16;     // 641 vertex groups
__global__ __launch_bounds__(256) void k_aggvp(const ushort* __restrict__ h, ushort* __restrict__ xo,
                                               const int* __restrict__ rp, const int* __restrict__ ci,
                                               const float* __restrict__ val) {
    const int bid = blockIdx.x;
    const int xcd = bid & 7;
    const int g = bid >> 3;
    const int round = g / NVG16;          // 0..3
    const int vg = g - round * NVG16;
    const int panel = xcd + round * 8;    // 0..31
    const int t = threadIdx.x;
    const int i = vg * 16 + (t >> 4);
    if (i >= NV) return;                  // no barriers below
    const int po = panel * 128 + (t & 15) * 8;   // offset within 4096-elem chunk
    const ushort* hb = h + po;
    const int r0 = rp[i], r1 = rp[i + 1];
    float acc[8] = {};
    for (int e = r0; e < r1; e += 4) {
        const bool p1 = e + 1 < r1, p2 = e + 2 < r1, p3 = e + 3 < r1;
        const int j0 = ci[e];
        const int j1 = p1 ? ci[e + 1] : j0;
        const int j2 = p2 ? ci[e + 2] : j0;
        const int j3 = p3 ? ci[e + 3] : j0;
        const float w0 = val[e];
        const float w1 = p1 ? val[e + 1] : 0.f;
        const float w2 = p2 ? val[e + 2] : 0.f;
        const float w3 = p3 ? val[e + 3] : 0.f;
        const short8_t v0 = *(const short8_t*)(hb + (size_t)j0 * 4096);
        const short8_t v1 = *(const short8_t*)(hb + (size_t)j1 * 4096);
        const short8_t v2 = *(const short8_t*)(hb + (size_t)j2 * 4096);
        const short8_t v3 = *(const short8_t*)(hb + (size_t)j3 * 4096);
        #pragma unroll
        for (int k = 0; k < 8; ++k) {
            float a = acc[k];
            a = fmaf(w0, bf2f((ushort)v0[k]), a);
            a = fmaf(w1, bf2f((ushort)v1[k]), a);
            a = fmaf(w2, bf2f((ushort)v2[k]), a);
            a = fmaf(w3, bf2f((ushort)v3[k]), a);
            acc[k] = a;
        }
    }
    short8_t o;
    #pragma unroll
    for (int k = 0; k < 8; ++k) o[k] = (short)f2bf(acc[k]);
    *(short8_t*)(xo + (size_t)i * 4096 + po) = o;
}

// ---------------- fused 64-wide agg + layer-6 matvec ----------------
__global__ __launch_bounds__(64) void k_aggv64f(const ushort* __restrict__ h, float* __restrict__ h3,
                                                const int* __restrict__ rp, const int* __restrict__ ci,
                                                const float* __restrict__ val, const float* __restrict__ b5,
                                                const float* __restrict__ W6) {
    constexpr int CH = BB * 64;
    __shared__ float w6[192];
    const int t = threadIdx.x;
    w6[t] = W6[t]; w6[t + 64] = W6[t + 64]; w6[t + 128] = W6[t + 128];
    __syncthreads();
    const int i = blockIdx.x;
    const int r0 = rp[i], r1 = rp[i + 1];
    const ushort* hb = h + t * 8;
    float acc[8] = {};
    for (int e = r0; e < r1; e += 4) {
        const bool p1 = e + 1 < r1, p2 = e + 2 < r1, p3 = e + 3 < r1;
        const int j0 = ci[e];
        const int j1 = p1 ? ci[e + 1] : j0;
        const int j2 = p2 ? ci[e + 2] : j0;
        const int j3 = p3 ? ci[e + 3] : j0;
        const float w0 = val[e];
        const float w1 = p1 ? val[e + 1] : 0.f;
        const float w2 = p2 ? val[e + 2] : 0.f;
        const float w3 = p3 ? val[e + 3] : 0.f;
        const short8_t v0 = *(const short8_t*)(hb + (size_t)j0 * CH);
        const short8_t v1 = *(const short8_t*)(hb + (size_t)j1 * CH);
        const short8_t v2 = *(const short8_t*)(hb + (size_t)j2 * CH);
        const short8_t v3 = *(const short8_t*)(hb + (size_t)j3 * CH);
        #pragma unroll
        for (int k = 0; k < 8; ++k) {
            float a = acc[k];
            a = fmaf(w0, bf2f((ushort)v0[k]), a);
            a = fmaf(w1, bf2f((ushort)v1[k]), a);
            a = fmaf(w2, bf2f((ushort)v2[k]), a);
            a = fmaf(w3, bf2f((ushort)v3[k]), a);
            acc[k] = a;
        }
    }
    const int fb = (t & 7) * 8;
    float p0 = 0.f, p1 = 0.f, p2 = 0.f;
    #pragma unroll
    for (int k = 0; k < 8; ++k) {
        float a = acc[k] + b5[fb + k];
        p0 = fmaf(a, w6[(fb + k) * 3 + 0], p0);
        p1 = fmaf(a, w6[(fb + k) * 3 + 1], p1);
        p2 = fmaf(a, w6[(fb + k) * 3 + 2], p2);
    }
    p0 += __shfl_xor(p0, 1); p0 += __shfl_xor(p0, 2); p0 += __shfl_xor(p0, 4);
    p1 += __shfl_xor(p1, 1); p1 += __shfl_xor(p1, 2); p1 += __shfl_xor(p1, 4);
    p2 += __shfl_xor(p2, 1); p2 += __shfl_xor(p2, 2); p2 += __shfl_xor(p2, 4);
    if ((t & 7) == 0) {
        int row = i * 8 + (t >> 3);
        float* o = h3 + (size_t)row * 3;
        o[0] = p0; o[1] = p1; o[2] = p2;
    }
}

// final aggregation: h3 vertex-major [i*8+b][3] -> out [b][i][3]
__global__ __launch_bounds__(256) void k_agg3(const float* __restrict__ h3, float* __restrict__ out,
                                              const int* __restrict__ rp, const int* __restrict__ ci,
                                              const float* __restrict__ val, const float* __restrict__ b6) {
    int idx = blockIdx.x * 256 + threadIdx.x;
    if (idx >= MROWS) return;
    int b = idx / NV, i = idx - b * NV;
    float a0 = b6[0], a1 = b6[1], a2 = b6[2];
    int r0 = rp[i], r1 = rp[i + 1];
    for (int e = r0; e < r1; ++e) {
        int j = ci[e];
        float wv = val[e];
        const float* hr = h3 + ((size_t)j * BB + b) * 3;
        a0 = fmaf(wv, hr[0], a0);
        a1 = fmaf(wv, hr[1], a1);
        a2 = fmaf(wv, hr[2], a2);
    }
    float* o = out + (size_t)idx * 3;
    o[0] = a0; o[1] = a1; o[2] = a2;
}

// ---------------- launcher ----------------
extern "C" void kernel_launch(void* const* d_in, const int* in_sizes, int n_in,
                              void* d_out, int out_size, void* d_ws, size_t ws_size,
                              hipStream_t stream) {
    const float* verts = (const float*)d_in[0];
    const float* img   = (const float*)d_in[1];
    const int*   ei    = (const int*)d_in[2];
    const float* W1 = (const float*)d_in[3];  const float* b1 = (const float*)d_in[4];
    const float* W2 = (const float*)d_in[5];  const float* b2 = (const float*)d_in[6];
    const float* W3 = (const float*)d_in[7];  const float* b3 = (const float*)d_in[8];
    const float* W4 = (const float*)d_in[9];  const float* b4 = (const float*)d_in[10];
    const float* W5 = (const float*)d_in[11]; const float* b5 = (const float*)d_in[12];
    const float* W6 = (const float*)d_in[13]; const float* b6 = (const float*)d_in[14];
    float* out = (float*)d_out;

    char* ws = (char*)d_ws;
    size_t off = 0;
    auto carve = [&](size_t bytes) -> void* {
        void* q = ws + off;
        off += (bytes + 255) & ~(size_t)255;
        return q;
    };
    ushort* bufA = (ushort*)carve((size_t)MROWS * 512 * 2);   // R / z / h5
    ushort* bufB = (ushort*)carve((size_t)MROWS * 512 * 2);   // y3 / r4
    ushort* Wt4  = (ushort*)carve((size_t)512 * 512 * 2);
    ushort* W3c  = (ushort*)carve((size_t)512 * 512 * 2);
    ushort* Wt34 = (ushort*)carve((size_t)512 * 512 * 2);
    ushort* Wt5  = (ushort*)carve((size_t)64 * 512 * 2);
    float*  basev = (float*)carve((size_t)BB * 512 * 4);
    float*  bw2   = (float*)carve((size_t)BB * 512 * 4);
    float*  CW12  = (float*)carve((size_t)3 * 512 * 4);
    float*  b1w2  = (float*)carve((size_t)512 * 4);
    float*  b3w4  = (float*)carve((size_t)512 * 4);
    int*    deg  = (int*)carve((size_t)NV * 4);
    int*    fill = (int*)carve((size_t)NV * 4);
    float*  sV   = (float*)carve((size_t)NV * 4);
    float*  s2V  = (float*)carve((size_t)NV * 4);
    int*    rp   = (int*)carve((size_t)(NV + 1) * 4);
    int*    ci   = (int*)carve((size_t)NET * 4);
    float*  valv = (float*)carve((size_t)NET * 4);
    float*  aggV  = (float*)carve((size_t)MROWS * 3 * 4);
    float*  aggV2 = (float*)carve((size_t)MROWS * 3 * 4);
    float*  h3   = (float*)carve((size_t)MROWS * 3 * 4);

    dim3 b256(256);
    const int gNV = (NV + 255) / 256;
    const int gMR = (MROWS + 255) / 256;
    // CSR build
    k_init<<<dim3(gNV), b256, 0, stream>>>(deg, fill);
    k_count<<<dim3((NE + 255) / 256), b256, 0, stream>>>(ei, deg);
    k_scan<<<dim3(1), dim3(1024), 0, stream>>>(deg, rp);
    k_fill<<<dim3((NET + 255) / 256), b256, 0, stream>>>(ei, rp, fill, deg, ci, valv);
    // pass1: aggV = A*verts + sV = A*1 ; pass2: aggV2 = A*aggV + s2V = A*sV
    k_aggsc<<<dim3(gMR + gNV), b256, 0, stream>>>(verts, aggV, rp, ci, valv, nullptr, sV, gMR);
    k_aggsc<<<dim3(gMR + gNV), b256, 0, stream>>>(aggV, aggV2, rp, ci, valv, sV, s2V, gMR);
    // merged prep + bw2 + composite W3*W4
    k_prep<<<dim3(2176 + 10 + 16), b256, 0, stream>>>(W4, W3, W5, W1, b1, b3, W2, img,
                                                      Wt4, W3c, Wt5, CW12, b1w2, b3w4, basev);
    k_matvecs<<<dim3(4, BB), dim3(128), 0, stream>>>(basev, W2, bw2);
    k_gemm<0><<<dim3(32), b256, 0, stream>>>(Wt4, W3c, Wt34, 512, 512, nullptr, nullptr, nullptr);
    // R = relu(x2) materialized -> bufA
    k_x2<<<dim3((MROWS + 1) / 2), b256, 0, stream>>>(aggV2, sV, s2V, CW12, bw2, b1w2, b2, bufA);
    // y3 = A*R -> bufB ; z = A*y3 -> bufA   (panel-partitioned, XCD-L2-resident)
    const int gP = 8 * 4 * NVG16;   // 20512
    k_aggvp<<<dim3(gP), b256, 0, stream>>>(bufA, bufB, rp, ci, valv);
    k_aggvp<<<dim3(gP), b256, 0, stream>>>(bufB, bufA, rp, ci, valv);
    // r4 = relu(z*W34 + s*b3w4 + b4) -> bufB   (BM=256 x BN=128 tile)
    const int nrc = (MROWS + 255) / 256;            // 321
    const int g512 = 8 * ((nrc + 7) / 8) * 4;       // 1312
    k_gemm<1><<<dim3(g512), b256, 0, stream>>>(bufA, Wt34, bufB, MROWS, 512, sV, b3w4, b4);
    // layer 5: h5 = r4*W5 -> bufA
    k_gemm64<<<dim3((MROWS + 255) / 256), b256, 0, stream>>>(bufB, Wt5, bufA);
    // fused: x5 = A*h5 + b5 ; h3 = x5*W6
    k_aggv64f<<<dim3(NV), dim3(64), 0, stream>>>(bufA, h3, rp, ci, valv, b5, W6);
    // final aggregation into d_out
    k_agg3<<<dim3(gMR), b256, 0, stream>>>(h3, out, rp, ci, valv, b6);
}

// Round 16
// 391.325 us; speedup vs baseline: 1.2647x; 1.2647x over previous
//
#include <hip/hip_runtime.h>
#include <hip/hip_bf16.h>

typedef __attribute__((ext_vector_type(8))) short short8_t;
typedef __attribute__((ext_vector_type(4))) float f32x4;

#define DEV __device__ __forceinline__

constexpr int BB = 8;           // batch
constexpr int NV = 10242;       // vertices
constexpr int NE = 61440;       // edges
constexpr int NET = NE + NV;    // total CSR edges (with self-loops)
constexpr int MROWS = BB * NV;  // 81936
constexpr int KD = 512;         // K for 512-wide GEMMs

DEV float bf2f(ushort u) { union { unsigned i; float f; } v; v.i = ((unsigned)u) << 16; return v.f; }
DEV ushort f2bf(float f) {
    union { unsigned i; float f; } v; v.f = f;
    unsigned b = v.i;
    b += 0x7fffu + ((b >> 16) & 1u);   // RNE
    return (ushort)(b >> 16);
}

// ---------------- CSR build ----------------
__global__ void k_init(int* deg, int* fill) {
    int i = blockIdx.x * 256 + threadIdx.x;
    if (i < NV) { deg[i] = 1; fill[i] = 0; }   // self-loop counts as 1
}

__global__ void k_count(const int* __restrict__ ei, int* __restrict__ deg) {
    int e = blockIdx.x * 256 + threadIdx.x;
    if (e < NE) atomicAdd(&deg[ei[NE + e]], 1);   // dst row
}

__global__ __launch_bounds__(1024) void k_scan(const int* __restrict__ cnt, int* __restrict__ rp) {
    __shared__ int part[1024];
    const int t = threadIdx.x;
    const int chunk = (NV + 1023) / 1024;   // 11
    int b0 = t * chunk, b1 = min(b0 + chunk, NV);
    int s = 0;
    for (int i = b0; i < b1; ++i) s += cnt[i];
    part[t] = s;
    __syncthreads();
    for (int off = 1; off < 1024; off <<= 1) {
        int v = (t >= off) ? part[t - off] : 0;
        __syncthreads();
        part[t] += v;
        __syncthreads();
    }
    int run = (t == 0) ? 0 : part[t - 1];
    for (int i = b0; i < b1; ++i) { rp[i] = run; run += cnt[i]; }
    if (t == 1023) rp[NV] = part[1023];
}

__global__ void k_fill(const int* __restrict__ ei, const int* __restrict__ rp,
                       int* __restrict__ fill, const int* __restrict__ deg,
                       int* __restrict__ ci, float* __restrict__ val) {
    int e = blockIdx.x * 256 + threadIdx.x;
    if (e >= NET) return;
    int s, d;
    if (e < NE) { s = ei[e]; d = ei[NE + e]; }
    else        { s = d = e - NE; }           // self-loops
    int p = atomicAdd(&fill[d], 1);
    int pos = rp[d] + p;
    ci[pos] = s;
    val[pos] = rsqrtf((float)deg[s]) * rsqrtf((float)deg[d]);
}

// ---------------- merged 3-wide agg + scalar chain ----------------
__global__ __launch_bounds__(256) void k_aggsc(const float* __restrict__ src, float* __restrict__ dst,
                                               const int* __restrict__ rp, const int* __restrict__ ci,
                                               const float* __restrict__ val,
                                               const float* __restrict__ sin, float* __restrict__ sout,
                                               int gMR_) {
    const int bid = blockIdx.x;
    if (bid < gMR_) {
        int idx = bid * 256 + threadIdx.x;
        if (idx >= MROWS) return;
        int b = idx / NV, i = idx - b * NV;
        float a0 = 0.f, a1 = 0.f, a2 = 0.f;
        const float* sb = src + (size_t)b * NV * 3;
        for (int e = rp[i]; e < rp[i + 1]; ++e) {
            int j = ci[e];
            float wv = val[e];
            a0 = fmaf(wv, sb[j * 3 + 0], a0);
            a1 = fmaf(wv, sb[j * 3 + 1], a1);
            a2 = fmaf(wv, sb[j * 3 + 2], a2);
        }
        float* o = dst + ((size_t)b * NV + i) * 3;
        o[0] = a0; o[1] = a1; o[2] = a2;
    } else {
        int i = (bid - gMR_) * 256 + threadIdx.x;
        if (i >= NV) return;
        float a = 0.f;
        if (sin) { for (int e = rp[i]; e < rp[i + 1]; ++e) a = fmaf(val[e], sin[ci[e]], a); }
        else     { for (int e = rp[i]; e < rp[i + 1]; ++e) a += val[e]; }
        sout[i] = a;
    }
}

// ---------------- merged prep: weight convert + small matvecs + l1base ----------------
__global__ __launch_bounds__(256) void k_prep(const float* __restrict__ W4, const float* __restrict__ W3,
                                              const float* __restrict__ W5, const float* __restrict__ W1,
                                              const float* __restrict__ b1, const float* __restrict__ b3,
                                              const float* __restrict__ W2, const float* __restrict__ img,
                                              ushort* __restrict__ Wt4, ushort* __restrict__ W3c,
                                              ushort* __restrict__ Wt5, float* __restrict__ CW12,
                                              float* __restrict__ b1w2, float* __restrict__ b3w4,
                                              float* __restrict__ basev) {
    constexpr int WB = (2 * 512 * 512 + 64 * 512) / 256;   // 2176
    const int bid = blockIdx.x;
    const int t = threadIdx.x;
    if (bid < WB) {
        int idx = bid * 256 + t;
        if (idx < 512 * 512) {
            int n = idx >> 9, k = idx & 511;
            Wt4[idx] = f2bf(W4[k * 512 + n]);
        } else if (idx < 2 * 512 * 512) {
            int j = idx - 512 * 512;
            W3c[j] = f2bf(W3[j]);
        } else {
            int j = idx - 2 * 512 * 512;
            int n = j >> 9, k = j & 511;
            Wt5[j] = f2bf(W5[k * 64 + n]);
        }
    } else if (bid < WB + 10) {
        int r = bid - WB;
        int y = r >> 1;
        int c = (r & 1) * 256 + t;
        const float* Mrow = (y < 3) ? (W1 + y * 512) : (y == 3 ? b1 : b3);
        const float* W = (y < 4) ? W2 : W4;
        float a = 0.f;
        for (int k = 0; k < 512; ++k) a = fmaf(Mrow[k], W[(size_t)k * 512 + c], a);
        float* o = (y < 3) ? (CW12 + y * 512) : (y == 3 ? b1w2 : b3w4);
        o[c] = a;
    } else {
        int r = bid - (WB + 10);
        int b = r >> 1;
        int c = (r & 1) * 256 + t;
        float s = 0.f;
        for (int k = 0; k < 512; ++k) s = fmaf(img[b * 512 + k], W1[(size_t)(3 + k) * 512 + c], s);
        basev[b * 512 + c] = s;
    }
}

// bw2[r][c] = sum_k basev[r][k]*W2[k][c]
__global__ __launch_bounds__(128) void k_matvecs(const float* __restrict__ M, const float* __restrict__ W,
                                                 float* __restrict__ out) {
    int c = blockIdx.x * 128 + threadIdx.x;
    int r = blockIdx.y;
    float a = 0.f;
    for (int k = 0; k < 512; ++k) a = fmaf(M[r * 512 + k], W[(size_t)k * 512 + c], a);
    out[r * 512 + c] = a;
}

// ---------------- x2 reconstruction (layers 1-2 collapsed), R = relu(x2) -> bf16 ----------------
__global__ __launch_bounds__(256) void k_x2(const float* __restrict__ aggV2, const float* __restrict__ s,
                                            const float* __restrict__ s2, const float* __restrict__ CW12,
                                            const float* __restrict__ bw2, const float* __restrict__ b1w2,
                                            const float* __restrict__ b2, ushort* __restrict__ r2) {
    const int t = threadIdx.x;
    int row = blockIdx.x * 2 + (t >> 7);
    if (row >= MROWS) return;
    int i = row >> 3, b = row & 7;
    const float* av = aggV2 + ((size_t)b * NV + i) * 3;
    float a0 = av[0], a1 = av[1], a2 = av[2];
    float si = s[i], s2i = s2[i];
    int c = (t & 127) * 4;
    float4 w0 = *(const float4*)&CW12[c];
    float4 w1 = *(const float4*)&CW12[512 + c];
    float4 w2 = *(const float4*)&CW12[1024 + c];
    float4 bw = *(const float4*)&bw2[b * 512 + c];
    float4 bv = *(const float4*)&b1w2[c];
    float4 b2v = *(const float4*)&b2[c];
    float o0 = a0 * w0.x + a1 * w1.x + a2 * w2.x + s2i * bw.x + si * bv.x + b2v.x;
    float o1 = a0 * w0.y + a1 * w1.y + a2 * w2.y + s2i * bw.y + si * bv.y + b2v.y;
    float o2 = a0 * w0.z + a1 * w1.z + a2 * w2.z + s2i * bw.z + si * bv.z + b2v.z;
    float o3 = a0 * w0.w + a1 * w1.w + a2 * w2.w + s2i * bw.w + si * bv.w + b2v.w;
    ushort4 o;
    o.x = f2bf(fmaxf(o0, 0.f));
    o.y = f2bf(fmaxf(o1, 0.f));
    o.z = f2bf(fmaxf(o2, 0.f));
    o.w = f2bf(fmaxf(o3, 0.f));
    *(ushort4*)&r2[(size_t)row * 512 + c] = o;
}

#define WAITVM(n) do { \
    asm volatile("s_waitcnt vmcnt(" #n ")" ::: "memory"); \
    __builtin_amdgcn_sched_barrier(0); \
    __builtin_amdgcn_s_barrier(); \
    __builtin_amdgcn_sched_barrier(0); \
} while (0)

// ---------------- GEMM: C[M,Nc] = A[M,512] @ Bt[Nc,512]^T ----------------
// 128x128 tile, XOR-swizzled LDS, swapped-MFMA C^T frags, ushort4 stores,
// T4 counted-vmcnt 3-buffer pipeline (R10/R14 proven: 86us, MfmaUtil 20%).
// R15's 256x128 tile dropped occupancy to ~1 block/CU (72KB x3 LDS) -> 178us;
// occupancy, not ds_read economy, is the binding constraint at this structure.
template <int EPI>
__global__ __launch_bounds__(256) void k_gemm(const ushort* __restrict__ A, const ushort* __restrict__ Bt,
                                              ushort* __restrict__ C, int Mr, int Nc,
                                              const float* __restrict__ sv, const float* __restrict__ eb1,
                                              const float* __restrict__ eb2) {
    const int ncb = (Nc + 127) >> 7;
    const int nrc = (Mr + 127) >> 7;
    const int cpx = (nrc + 7) >> 3;
    const int bid = blockIdx.x;
    const int xcd = bid & 7;
    const int k = bid >> 3;
    const int rc = xcd * cpx + k / ncb;
    const int cb = k % ncb;
    if (rc >= nrc) return;

    __shared__ __align__(16) ushort lA[3][4096];
    __shared__ __align__(16) ushort lB[3][4096];
    const int t = threadIdx.x;
    const int lane = t & 63, w = t >> 6;
    const int wr = w >> 1, wc = w & 1;
    const int r0 = rc * 128, c0 = cb * 128;

    const ushort* gA[2]; const ushort* gB[2];
    int ldsoff[2];
    #pragma unroll
    for (int i2 = 0; i2 < 2; ++i2) {
        int idx = i2 * 256 + t;
        int row = idx >> 2, slot = idx & 3;
        int srcslot = slot ^ ((row >> 1) & 3);
        int ar = min(r0 + row, Mr - 1);
        int bc = min(c0 + row, Nc - 1);
        gA[i2] = A + (size_t)ar * KD + srcslot * 8;
        gB[i2] = Bt + (size_t)bc * KD + srcslot * 8;
        ldsoff[i2] = idx * 8;
    }

    auto stage = [&](int buf, int kt) {
        int ko = kt * 32;
        #pragma unroll
        for (int i2 = 0; i2 < 2; ++i2) {
            __builtin_amdgcn_global_load_lds(
                (const __attribute__((address_space(1))) void*)(gA[i2] + ko),
                (__attribute__((address_space(3))) void*)(&lA[buf][ldsoff[i2]]), 16, 0, 0);
            __builtin_amdgcn_global_load_lds(
                (const __attribute__((address_space(1))) void*)(gB[i2] + ko),
                (__attribute__((address_space(3))) void*)(&lB[buf][ldsoff[i2]]), 16, 0, 0);
        }
    };

    f32x4 acc[4][4] = {};
    const int rloc = lane & 15;
    const int kb = lane >> 4;
    const int kbs = (kb ^ ((rloc >> 1) & 3)) * 8;

    auto compute = [&](int buf) {
        short8_t af[4], bfr[4];
        #pragma unroll
        for (int m = 0; m < 4; ++m) {
            af[m]  = *(const short8_t*)&lA[buf][(wr * 64 + m * 16 + rloc) * 32 + kbs];
            bfr[m] = *(const short8_t*)&lB[buf][(wc * 64 + m * 16 + rloc) * 32 + kbs];
        }
        #pragma unroll
        for (int m = 0; m < 4; ++m)
            #pragma unroll
            for (int n = 0; n < 4; ++n)   // swapped operands -> C^T fragment
                acc[m][n] = __builtin_amdgcn_mfma_f32_16x16x32_bf16(bfr[n], af[m], acc[m][n], 0, 0, 0);
    };

    stage(0, 0);
    stage(1, 1);
    WAITVM(4);
    int cur = 0;
    for (int kt = 0; kt < 14; ++kt) {
        int sb = cur + 2; if (sb > 2) sb -= 3;
        stage(sb, kt + 2);
        compute(cur);
        WAITVM(4);
        cur = (cur == 2) ? 0 : cur + 1;
    }
    compute(cur);
    WAITVM(0);
    cur = (cur == 2) ? 0 : cur + 1;
    compute(cur);

    #pragma unroll
    for (int m = 0; m < 4; ++m) {
        const int gr = r0 + wr * 64 + m * 16 + rloc;
        if (gr >= Mr) continue;
        #pragma unroll
        for (int n = 0; n < 4; ++n) {
            const int qc = c0 + wc * 64 + n * 16;
            if (qc >= Nc) continue;
            const int gc = qc + kb * 4;
            float v0 = acc[m][n][0], v1 = acc[m][n][1], v2 = acc[m][n][2], v3 = acc[m][n][3];
            if (EPI == 1) {
                const float s = sv[gr >> 3];
                const float4 e1 = *(const float4*)&eb1[gc];
                const float4 e2 = *(const float4*)&eb2[gc];
                v0 = fmaxf(v0 + s * e1.x + e2.x, 0.f);
                v1 = fmaxf(v1 + s * e1.y + e2.y, 0.f);
                v2 = fmaxf(v2 + s * e1.z + e2.z, 0.f);
                v3 = fmaxf(v3 + s * e1.w + e2.w, 0.f);
            }
            ushort4 o;
            o.x = f2bf(v0); o.y = f2bf(v1); o.z = f2bf(v2); o.w = f2bf(v3);
            *(ushort4*)&C[(size_t)gr * Nc + gc] = o;
        }
    }
}

// ---------------- specialized GEMM for Nc=64 ----------------
__global__ __launch_bounds__(256) void k_gemm64(const ushort* __restrict__ A, const ushort* __restrict__ Bt,
                                                ushort* __restrict__ C) {
    const int rc = blockIdx.x;
    const int r0 = rc * 256;
    __shared__ __align__(16) ushort lA[2][8192];
    __shared__ __align__(16) ushort lB[2][2048];
    const int t = threadIdx.x;
    const int lane = t & 63, w = t >> 6;

    const ushort* gA[4]; int loffA[4];
    #pragma unroll
    for (int p = 0; p < 4; ++p) {
        int idx = p * 256 + t;
        int row = idx >> 2, slot = idx & 3;
        int srcslot = slot ^ ((row >> 1) & 3);
        int ar = min(r0 + row, MROWS - 1);
        gA[p] = A + (size_t)ar * KD + srcslot * 8;
        loffA[p] = idx * 8;
    }
    const int brow = t >> 2, bslot = (t & 3) ^ ((brow >> 1) & 3);
    const ushort* gB = Bt + (size_t)brow * KD + bslot * 8;
    const int loffB = t * 8;

    auto stage = [&](int buf, int kt) {
        int ko = kt * 32;
        #pragma unroll
        for (int p = 0; p < 4; ++p)
            __builtin_amdgcn_global_load_lds(
                (const __attribute__((address_space(1))) void*)(gA[p] + ko),
                (__attribute__((address_space(3))) void*)(&lA[buf][loffA[p]]), 16, 0, 0);
        __builtin_amdgcn_global_load_lds(
            (const __attribute__((address_space(1))) void*)(gB + ko),
            (__attribute__((address_space(3))) void*)(&lB[buf][loffB]), 16, 0, 0);
    };

    f32x4 acc[4][4] = {};
    stage(0, 0);
    __syncthreads();
    int cur = 0;
    const int rloc = lane & 15;
    const int kb = lane >> 4;
    const int kbs = (kb ^ ((rloc >> 1) & 3)) * 8;
    for (int kt = 0; kt < 16; ++kt) {
        if (kt < 15) stage(cur ^ 1, kt + 1);
        short8_t af[4], bfr[4];
        #pragma unroll
        for (int m = 0; m < 4; ++m) {
            af[m]  = *(const short8_t*)&lA[cur][(w * 64 + m * 16 + rloc) * 32 + kbs];
            bfr[m] = *(const short8_t*)&lB[cur][(m * 16 + rloc) * 32 + kbs];
        }
        #pragma unroll
        for (int m = 0; m < 4; ++m)
            #pragma unroll
            for (int n = 0; n < 4; ++n)
                acc[m][n] = __builtin_amdgcn_mfma_f32_16x16x32_bf16(bfr[n], af[m], acc[m][n], 0, 0, 0);
        __syncthreads();
        cur ^= 1;
    }

    #pragma unroll
    for (int m = 0; m < 4; ++m) {
        const int gr = r0 + w * 64 + m * 16 + rloc;
        if (gr >= MROWS) continue;
        #pragma unroll
        for (int n = 0; n < 4; ++n) {
            const int gc = n * 16 + kb * 4;
            ushort4 o;
            o.x = f2bf(acc[m][n][0]); o.y = f2bf(acc[m][n][1]);
            o.z = f2bf(acc[m][n][2]); o.w = f2bf(acc[m][n][3]);
            *(ushort4*)&C[(size_t)gr * 64 + gc] = o;
        }
    }
}

// ---------------- PANEL-partitioned 512-wide aggregation (XCD-L2-resident gathers) ----------------
constexpr int NVG16 = (NV + 15) / 16;     // 641 vertex groups
__global__ __launch_bounds__(256) void k_aggvp(const ushort* __restrict__ h, ushort* __restrict__ xo,
                                               const int* __restrict__ rp, const int* __restrict__ ci,
                                               const float* __restrict__ val) {
    const int bid = blockIdx.x;
    const int xcd = bid & 7;
    const int g = bid >> 3;
    const int round = g / NVG16;          // 0..3
    const int vg = g - round * NVG16;
    const int panel = xcd + round * 8;    // 0..31
    const int t = threadIdx.x;
    const int i = vg * 16 + (t >> 4);
    if (i >= NV) return;                  // no barriers below
    const int po = panel * 128 + (t & 15) * 8;   // offset within 4096-elem chunk
    const ushort* hb = h + po;
    const int r0 = rp[i], r1 = rp[i + 1];
    float acc[8] = {};
    for (int e = r0; e < r1; e += 4) {
        const bool p1 = e + 1 < r1, p2 = e + 2 < r1, p3 = e + 3 < r1;
        const int j0 = ci[e];
        const int j1 = p1 ? ci[e + 1] : j0;
        const int j2 = p2 ? ci[e + 2] : j0;
        const int j3 = p3 ? ci[e + 3] : j0;
        const float w0 = val[e];
        const float w1 = p1 ? val[e + 1] : 0.f;
        const float w2 = p2 ? val[e + 2] : 0.f;
        const float w3 = p3 ? val[e + 3] : 0.f;
        const short8_t v0 = *(const short8_t*)(hb + (size_t)j0 * 4096);
        const short8_t v1 = *(const short8_t*)(hb + (size_t)j1 * 4096);
        const short8_t v2 = *(const short8_t*)(hb + (size_t)j2 * 4096);
        const short8_t v3 = *(const short8_t*)(hb + (size_t)j3 * 4096);
        #pragma unroll
        for (int k = 0; k < 8; ++k) {
            float a = acc[k];
            a = fmaf(w0, bf2f((ushort)v0[k]), a);
            a = fmaf(w1, bf2f((ushort)v1[k]), a);
            a = fmaf(w2, bf2f((ushort)v2[k]), a);
            a = fmaf(w3, bf2f((ushort)v3[k]), a);
            acc[k] = a;
        }
    }
    short8_t o;
    #pragma unroll
    for (int k = 0; k < 8; ++k) o[k] = (short)f2bf(acc[k]);
    *(short8_t*)(xo + (size_t)i * 4096 + po) = o;
}

// ---------------- fused 64-wide agg + layer-6 matvec ----------------
__global__ __launch_bounds__(64) void k_aggv64f(const ushort* __restrict__ h, float* __restrict__ h3,
                                                const int* __restrict__ rp, const int* __restrict__ ci,
                                                const float* __restrict__ val, const float* __restrict__ b5,
                                                const float* __restrict__ W6) {
    constexpr int CH = BB * 64;
    __shared__ float w6[192];
    const int t = threadIdx.x;
    w6[t] = W6[t]; w6[t + 64] = W6[t + 64]; w6[t + 128] = W6[t + 128];
    __syncthreads();
    const int i = blockIdx.x;
    const int r0 = rp[i], r1 = rp[i + 1];
    const ushort* hb = h + t * 8;
    float acc[8] = {};
    for (int e = r0; e < r1; e += 4) {
        const bool p1 = e + 1 < r1, p2 = e + 2 < r1, p3 = e + 3 < r1;
        const int j0 = ci[e];
        const int j1 = p1 ? ci[e + 1] : j0;
        const int j2 = p2 ? ci[e + 2] : j0;
        const int j3 = p3 ? ci[e + 3] : j0;
        const float w0 = val[e];
        const float w1 = p1 ? val[e + 1] : 0.f;
        const float w2 = p2 ? val[e + 2] : 0.f;
        const float w3 = p3 ? val[e + 3] : 0.f;
        const short8_t v0 = *(const short8_t*)(hb + (size_t)j0 * CH);
        const short8_t v1 = *(const short8_t*)(hb + (size_t)j1 * CH);
        const short8_t v2 = *(const short8_t*)(hb + (size_t)j2 * CH);
        const short8_t v3 = *(const short8_t*)(hb + (size_t)j3 * CH);
        #pragma unroll
        for (int k = 0; k < 8; ++k) {
            float a = acc[k];
            a = fmaf(w0, bf2f((ushort)v0[k]), a);
            a = fmaf(w1, bf2f((ushort)v1[k]), a);
            a = fmaf(w2, bf2f((ushort)v2[k]), a);
            a = fmaf(w3, bf2f((ushort)v3[k]), a);
            acc[k] = a;
        }
    }
    const int fb = (t & 7) * 8;
    float p0 = 0.f, p1 = 0.f, p2 = 0.f;
    #pragma unroll
    for (int k = 0; k < 8; ++k) {
        float a = acc[k] + b5[fb + k];
        p0 = fmaf(a, w6[(fb + k) * 3 + 0], p0);
        p1 = fmaf(a, w6[(fb + k) * 3 + 1], p1);
        p2 = fmaf(a, w6[(fb + k) * 3 + 2], p2);
    }
    p0 += __shfl_xor(p0, 1); p0 += __shfl_xor(p0, 2); p0 += __shfl_xor(p0, 4);
    p1 += __shfl_xor(p1, 1); p1 += __shfl_xor(p1, 2); p1 += __shfl_xor(p1, 4);
    p2 += __shfl_xor(p2, 1); p2 += __shfl_xor(p2, 2); p2 += __shfl_xor(p2, 4);
    if ((t & 7) == 0) {
        int row = i * 8 + (t >> 3);
        float* o = h3 + (size_t)row * 3;
        o[0] = p0; o[1] = p1; o[2] = p2;
    }
}

// final aggregation: h3 vertex-major [i*8+b][3] -> out [b][i][3]
__global__ __launch_bounds__(256) void k_agg3(const float* __restrict__ h3, float* __restrict__ out,
                                              const int* __restrict__ rp, const int* __restrict__ ci,
                                              const float* __restrict__ val, const float* __restrict__ b6) {
    int idx = blockIdx.x * 256 + threadIdx.x;
    if (idx >= MROWS) return;
    int b = idx / NV, i = idx - b * NV;
    float a0 = b6[0], a1 = b6[1], a2 = b6[2];
    int r0 = rp[i], r1 = rp[i + 1];
    for (int e = r0; e < r1; ++e) {
        int j = ci[e];
        float wv = val[e];
        const float* hr = h3 + ((size_t)j * BB + b) * 3;
        a0 = fmaf(wv, hr[0], a0);
        a1 = fmaf(wv, hr[1], a1);
        a2 = fmaf(wv, hr[2], a2);
    }
    float* o = out + (size_t)idx * 3;
    o[0] = a0; o[1] = a1; o[2] = a2;
}

// ---------------- launcher ----------------
extern "C" void kernel_launch(void* const* d_in, const int* in_sizes, int n_in,
                              void* d_out, int out_size, void* d_ws, size_t ws_size,
                              hipStream_t stream) {
    const float* verts = (const float*)d_in[0];
    const float* img   = (const float*)d_in[1];
    const int*   ei    = (const int*)d_in[2];
    const float* W1 = (const float*)d_in[3];  const float* b1 = (const float*)d_in[4];
    const float* W2 = (const float*)d_in[5];  const float* b2 = (const float*)d_in[6];
    const float* W3 = (const float*)d_in[7];  const float* b3 = (const float*)d_in[8];
    const float* W4 = (const float*)d_in[9];  const float* b4 = (const float*)d_in[10];
    const float* W5 = (const float*)d_in[11]; const float* b5 = (const float*)d_in[12];
    const float* W6 = (const float*)d_in[13]; const float* b6 = (const float*)d_in[14];
    float* out = (float*)d_out;

    char* ws = (char*)d_ws;
    size_t off = 0;
    auto carve = [&](size_t bytes) -> void* {
        void* q = ws + off;
        off += (bytes + 255) & ~(size_t)255;
        return q;
    };
    ushort* bufA = (ushort*)carve((size_t)MROWS * 512 * 2);   // R / z / h5
    ushort* bufB = (ushort*)carve((size_t)MROWS * 512 * 2);   // y3 / r4
    ushort* Wt4  = (ushort*)carve((size_t)512 * 512 * 2);
    ushort* W3c  = (ushort*)carve((size_t)512 * 512 * 2);
    ushort* Wt34 = (ushort*)carve((size_t)512 * 512 * 2);
    ushort* Wt5  = (ushort*)carve((size_t)64 * 512 * 2);
    float*  basev = (float*)carve((size_t)BB * 512 * 4);
    float*  bw2   = (float*)carve((size_t)BB * 512 * 4);
    float*  CW12  = (float*)carve((size_t)3 * 512 * 4);
    float*  b1w2  = (float*)carve((size_t)512 * 4);
    float*  b3w4  = (float*)carve((size_t)512 * 4);
    int*    deg  = (int*)carve((size_t)NV * 4);
    int*    fill = (int*)carve((size_t)NV * 4);
    float*  sV   = (float*)carve((size_t)NV * 4);
    float*  s2V  = (float*)carve((size_t)NV * 4);
    int*    rp   = (int*)carve((size_t)(NV + 1) * 4);
    int*    ci   = (int*)carve((size_t)NET * 4);
    float*  valv = (float*)carve((size_t)NET * 4);
    float*  aggV  = (float*)carve((size_t)MROWS * 3 * 4);
    float*  aggV2 = (float*)carve((size_t)MROWS * 3 * 4);
    float*  h3   = (float*)carve((size_t)MROWS * 3 * 4);

    dim3 b256(256);
    const int gNV = (NV + 255) / 256;
    const int gMR = (MROWS + 255) / 256;
    // CSR build
    k_init<<<dim3(gNV), b256, 0, stream>>>(deg, fill);
    k_count<<<dim3((NE + 255) / 256), b256, 0, stream>>>(ei, deg);
    k_scan<<<dim3(1), dim3(1024), 0, stream>>>(deg, rp);
    k_fill<<<dim3((NET + 255) / 256), b256, 0, stream>>>(ei, rp, fill, deg, ci, valv);
    // pass1: aggV = A*verts + sV = A*1 ; pass2: aggV2 = A*aggV + s2V = A*sV
    k_aggsc<<<dim3(gMR + gNV), b256, 0, stream>>>(verts, aggV, rp, ci, valv, nullptr, sV, gMR);
    k_aggsc<<<dim3(gMR + gNV), b256, 0, stream>>>(aggV, aggV2, rp, ci, valv, sV, s2V, gMR);
    // merged prep + bw2 + composite W3*W4
    k_prep<<<dim3(2176 + 10 + 16), b256, 0, stream>>>(W4, W3, W5, W1, b1, b3, W2, img,
                                                      Wt4, W3c, Wt5, CW12, b1w2, b3w4, basev);
    k_matvecs<<<dim3(4, BB), dim3(128), 0, stream>>>(basev, W2, bw2);
    k_gemm<0><<<dim3(32), b256, 0, stream>>>(Wt4, W3c, Wt34, 512, 512, nullptr, nullptr, nullptr);
    // R = relu(x2) materialized -> bufA
    k_x2<<<dim3((MROWS + 1) / 2), b256, 0, stream>>>(aggV2, sV, s2V, CW12, bw2, b1w2, b2, bufA);
    // y3 = A*R -> bufB ; z = A*y3 -> bufA   (panel-partitioned, XCD-L2-resident)
    const int gP = 8 * 4 * NVG16;   // 20512
    k_aggvp<<<dim3(gP), b256, 0, stream>>>(bufA, bufB, rp, ci, valv);
    k_aggvp<<<dim3(gP), b256, 0, stream>>>(bufB, bufA, rp, ci, valv);
    // r4 = relu(z*W34 + s*b3w4 + b4) -> bufB
    const int nrc = (MROWS + 127) / 128;            // 641
    const int g512 = 8 * ((nrc + 7) / 8) * 4;       // 2592
    k_gemm<1><<<dim3(g512), b256, 0, stream>>>(bufA, Wt34, bufB, MROWS, 512, sV, b3w4, b4);
    // layer 5: h5 = r4*W5 -> bufA
    k_gemm64<<<dim3((MROWS + 255) / 256), b256, 0, stream>>>(bufB, Wt5, bufA);
    // fused: x5 = A*h5 + b5 ; h3 = x5*W6
    k_aggv64f<<<dim3(NV), dim3(64), 0, stream>>>(bufA, h3, rp, ci, valv, b5, W6);
    // final aggregation into d_out
    k_agg3<<<dim3(gMR), b256, 0, stream>>>(h3, out, rp, ci, valv, b6);
}